// Round 5
// baseline (429.855 us; speedup 1.0000x reference)
//
#include <hip/hip_runtime.h>

#define E0     300000
#define E1     75000
#define NSRC0  50000
#define NDST0  20000
#define NDST1  5000
#define EMB    128
#define HID    256
#define NOUT   16

// ---------------- int degree histograms (CSR counts + out-degrees) ----------------
__global__ void hist_kernel(const int* __restrict__ src0, const int* __restrict__ dst0,
                            const int* __restrict__ src1, const int* __restrict__ dst1,
                            int* cnt0, int* cnt1, int* degO0, int* degO1) {
    int i = blockIdx.x * blockDim.x + threadIdx.x;
    if (i < E0) {
        atomicAdd(&cnt0[dst0[i]], 1);
        atomicAdd(&degO0[src0[i]], 1);
    }
    if (i < E1) {
        atomicAdd(&cnt1[dst1[i]], 1);
        atomicAdd(&degO1[src1[i]], 1);
    }
}

// ---------------- exclusive scan (2 blocks: graph0 bins, graph1 bins) ----------------
__device__ void scan_body(const int* __restrict__ cnt, int n,
                          int* __restrict__ off, int* __restrict__ cur) {
    __shared__ int sums[256];
    int t = threadIdx.x;
    int chunk = (n + 255) / 256;
    int lo = t * chunk, hi = min(lo + chunk, n);
    int s = 0;
    for (int i = lo; i < hi; ++i) s += cnt[i];
    sums[t] = s;
    __syncthreads();
    for (int d = 1; d < 256; d <<= 1) {
        int x = (t >= d) ? sums[t - d] : 0;
        __syncthreads();
        sums[t] += x;
        __syncthreads();
    }
    int run = (t == 0) ? 0 : sums[t - 1];
    for (int i = lo; i < hi; ++i) {
        off[i] = run; cur[i] = run;
        run += cnt[i];
    }
    if (t == 255) off[n] = run;
}

__global__ void scan_kernel(const int* cnt0, int* off0, int* cur0,
                            const int* cnt1, int* off1, int* cur1) {
    if (blockIdx.x == 0) scan_body(cnt0, NDST0, off0, cur0);
    else                 scan_body(cnt1, NDST1, off1, cur1);
}

// ---------------- bucket edges by dst (build CSR adjacency) ----------------
__global__ void bucket_kernel(const int* __restrict__ src0, const int* __restrict__ dst0,
                              const int* __restrict__ src1, const int* __restrict__ dst1,
                              int* cur0, int* cur1, int* esrc0, int* esrc1) {
    int i = blockIdx.x * blockDim.x + threadIdx.x;
    if (i < E0) {
        int p = atomicAdd(&cur0[dst0[i]], 1);
        esrc0[p] = src0[i];
    }
    if (i < E1) {
        int p = atomicAdd(&cur1[dst1[i]], 1);
        esrc1[p] = src1[i];
    }
}

// ---------------- per-node counting sort of the 50 word indices by 4MB vocab tile ----
// Tile = 8192 rows (8192*512B = 4MB = one XCD's L2). 7 tiles cover vocab 50000.
// All counters/offsets packed into 8-bit fields of two u32s -> pure registers.
__global__ void bucket_words_kernel(const int* __restrict__ user_word,
                                    int* __restrict__ words_sorted) {
    int node = blockIdx.x * blockDim.x + threadIdx.x;
    if (node >= NSRC0) return;
    const int* w = user_word + node * 50;
    int idxs[50];
    unsigned clo = 0, chi = 0;                 // per-tile counts, 8-bit fields
    #pragma unroll
    for (int j = 0; j < 50; ++j) {
        int v = w[j];
        idxs[j] = v;
        int b = v >> 13;                       // tile id 0..6
        if (b < 4) clo += 1u << (8 * b);
        else       chi += 1u << (8 * (b - 4));
    }
    int cnt[7];
    cnt[0] = clo & 255; cnt[1] = (clo >> 8) & 255; cnt[2] = (clo >> 16) & 255;
    cnt[3] = (clo >> 24) & 255;
    cnt[4] = chi & 255; cnt[5] = (chi >> 8) & 255; cnt[6] = (chi >> 16) & 255;
    unsigned olo = 0, ohi = 0;                 // exclusive prefix, 8-bit fields
    int run = 0;
    #pragma unroll
    for (int b = 0; b < 7; ++b) {
        if (b < 4) olo |= (unsigned)run << (8 * b);
        else       ohi |= (unsigned)run << (8 * (b - 4));
        run += cnt[b];
    }
    int* out = words_sorted + node * 50;
    #pragma unroll
    for (int j = 0; j < 50; ++j) {
        int v = idxs[j];
        int b = v >> 13;
        int sh = 8 * (b & 3);
        int pos;
        if (b < 4) { pos = (olo >> sh) & 255; olo += 1u << sh; }
        else       { pos = (ohi >> sh) & 255; ohi += 1u << sh; }
        out[pos] = v;
    }
}

// ---------------- fused embedding mean + out-degree scale (tile-swept float4 gather) --
// block = 256 threads = 8 groups of 32 lanes; group g handles node blockIdx*8+g.
// Indices are tile-sorted, so co-resident blocks sweep the table in the same
// order -> the active 4MB tile stays L2-resident per XCD.
__global__ void embed_kernel(const int* __restrict__ words_sorted,
                             const float* __restrict__ word_table,
                             const int* __restrict__ degO0,
                             float* __restrict__ x0) {
    __shared__ int idx[8 * 50];
    int t = threadIdx.x;
    for (int j = t; j < 8 * 50; j += 256)
        idx[j] = words_sorted[blockIdx.x * 400 + j];
    __syncthreads();
    int g = t >> 5, l = t & 31;
    int node = blockIdx.x * 8 + g;
    const float4* wt = (const float4*)word_table;   // row = 32 float4
    float ax = 0.f, ay = 0.f, az = 0.f, aw = 0.f;
    #pragma unroll 2
    for (int w = 0; w < 50; ++w) {
        float4 v = wt[idx[g * 50 + w] * 32 + l];
        ax += v.x; ay += v.y; az += v.z; aw += v.w;
    }
    float s = rsqrtf(fmaxf((float)degO0[node], 1.0f)) * 0.02f;  // 0.02 = 1/50 mean
    float4 o; o.x = ax * s; o.y = ay * s; o.z = az * s; o.w = aw * s;
    ((float4*)x0)[node * 32 + l] = o;
}

// ---------------- layer-1 gather-aggregate (float4, 1 wave/dst) ----------------
__global__ void agg1_kernel(const int* __restrict__ off0, const int* __restrict__ esrc0,
                            const float* __restrict__ x0, float* __restrict__ agg1) {
    int d = blockIdx.x;
    int t = threadIdx.x;               // 0..63
    int half = t >> 5, l = t & 31;
    int lo = off0[d], hi = off0[d + 1];
    const float4* x4 = (const float4*)x0;          // row = 32 float4
    float ax = 0.f, ay = 0.f, az = 0.f, aw = 0.f;
    for (int j = lo + half; j < hi; j += 2) {
        float4 v = x4[esrc0[j] * 32 + l];
        ax += v.x; ay += v.y; az += v.z; aw += v.w;
    }
    ax += __shfl_down(ax, 32); ay += __shfl_down(ay, 32);
    az += __shfl_down(az, 32); aw += __shfl_down(aw, 32);
    if (half == 0) {
        float sc = rsqrtf(fmaxf((float)(hi - lo), 1.0f));
        float4 o; o.x = ax * sc; o.y = ay * sc; o.z = az * sc; o.w = aw * sc;
        ((float4*)agg1)[d * 32 + l] = o;
    }
}

// ---------------- GEMM1: h1 = relu(agg1 @ W1 + b1) * rsqrt(deg_out1) ----------------
__global__ void gemm1_kernel(const float* __restrict__ agg1,
                             const int* __restrict__ degO1,
                             const float* __restrict__ W1, const float* __restrict__ b1,
                             float* __restrict__ h1) {
    __shared__ float A[16 * 128];
    __shared__ float s_out[16];
    int row0 = blockIdx.x * 16;
    int t = threadIdx.x;
    if (t < 16)
        s_out[t] = rsqrtf(fmaxf((float)degO1[row0 + t], 1.0f));
    for (int j = t; j < 16 * 128; j += 256)
        A[j] = agg1[row0 * 128 + j];
    __syncthreads();
    float acc[16];
    #pragma unroll
    for (int r = 0; r < 16; ++r) acc[r] = 0.0f;
    for (int k = 0; k < 128; ++k) {
        float w = W1[k * 256 + t];          // coalesced across t
        #pragma unroll
        for (int r = 0; r < 16; ++r)
            acc[r] += A[r * 128 + k] * w;   // LDS broadcast
    }
    float bb = b1[t];
    #pragma unroll
    for (int r = 0; r < 16; ++r)
        h1[(row0 + r) * 256 + t] = fmaxf(acc[r] + bb, 0.0f) * s_out[r];
}

// ---------------- layer-2 gather-aggregate (float4, 1 wave/dst, no reduce) ----------------
__global__ void agg2_kernel(const int* __restrict__ off1, const int* __restrict__ esrc1,
                            const float* __restrict__ h1, float* __restrict__ agg2) {
    int d = blockIdx.x;
    int l = threadIdx.x;               // 0..63
    int lo = off1[d], hi = off1[d + 1];
    const float4* h4 = (const float4*)h1;          // row = 64 float4
    float ax = 0.f, ay = 0.f, az = 0.f, aw = 0.f;
    int j = lo;
    for (; j + 1 < hi; j += 2) {
        float4 v0 = h4[esrc1[j] * 64 + l];
        float4 v1 = h4[esrc1[j + 1] * 64 + l];
        ax += v0.x + v1.x; ay += v0.y + v1.y;
        az += v0.z + v1.z; aw += v0.w + v1.w;
    }
    if (j < hi) {
        float4 v = h4[esrc1[j] * 64 + l];
        ax += v.x; ay += v.y; az += v.z; aw += v.w;
    }
    float sc = rsqrtf(fmaxf((float)(hi - lo), 1.0f));
    float4 o; o.x = ax * sc; o.y = ay * sc; o.z = az * sc; o.w = aw * sc;
    ((float4*)agg2)[d * 64 + l] = o;
}

// ---------------- GEMM2: out = relu(agg2 @ W2 + b2)  (+ labels passthrough) ----------------
__global__ void gemm2_kernel(const float* __restrict__ agg2,
                             const float* __restrict__ W2, const float* __restrict__ b2,
                             const int* __restrict__ labels,
                             float* __restrict__ out) {
    __shared__ float A[16 * 257];       // +1 pad: kills 16-way bank conflict
    __shared__ float Wl[256 * 16];
    int row0 = blockIdx.x * 16;
    int t = threadIdx.x;
    for (int j = t; j < 256 * 16; j += 256) Wl[j] = W2[j];
    for (int j = t; j < 16 * 256; j += 256) {
        int r = j >> 8, k = j & 255;
        int row = row0 + r;
        A[r * 257 + k] = (row < NDST1) ? agg2[row * 256 + k] : 0.0f;
    }
    __syncthreads();
    int r = t >> 4, c = t & 15;
    float acc = 0.0f;
    for (int k = 0; k < 256; ++k)
        acc += A[r * 257 + k] * Wl[k * 16 + c];
    int row = row0 + r;
    if (row < NDST1)
        out[row * NOUT + c] = fmaxf(acc + b2[c], 0.0f);
    if (t < 16 && row0 + t < NDST1)
        out[NDST1 * NOUT + row0 + t] = (float)labels[row0 + t];
}

extern "C" void kernel_launch(void* const* d_in, const int* in_sizes, int n_in,
                              void* d_out, int out_size, void* d_ws, size_t ws_size,
                              hipStream_t stream) {
    const int*   user_word  = (const int*)d_in[0];
    const int*   labels     = (const int*)d_in[1];
    const int*   src0       = (const int*)d_in[2];
    const int*   dst0       = (const int*)d_in[3];
    const int*   src1       = (const int*)d_in[4];
    const int*   dst1       = (const int*)d_in[5];
    const float* word_table = (const float*)d_in[6];
    const float* W1         = (const float*)d_in[7];
    const float* b1         = (const float*)d_in[8];
    const float* W2         = (const float*)d_in[9];
    const float* b2         = (const float*)d_in[10];

    int* iws = (int*)d_ws;
    int* cnt0  = iws;            // 20000  ┐
    int* cnt1  = iws + 20000;    //  5000  │ zeroed (95000 ints)
    int* degO0 = iws + 25000;    // 50000  │
    int* degO1 = iws + 75000;    // 20000  ┘
    int* off0  = iws + 95000;    // 20001
    int* off1  = iws + 115001;   //  5001
    int* cur0  = iws + 120002;   // 20000
    int* cur1  = iws + 140002;   //  5000
    int* esrc0 = iws + 145002;   // 300000
    int* esrc1 = iws + 445002;   // 75000
    int* wsort = iws + 520004;   // 2500000 (50000*50 tile-sorted word indices)
    float* x0   = (float*)(iws + 3020004); // 6400000 (50000*128)
    float* agg1 = x0 + 6400000;            // 2560000 (20000*128)
    float* h1   = x0;                      // alias: x0 dead after agg1_kernel
    float* agg2 = agg1 + 2560000;          // 1280000 (5000*256)
    // total ≈ (3020004 + 10240000) * 4 B ≈ 53 MB

    hipMemsetAsync(iws, 0, 95000 * sizeof(int), stream);

    bucket_words_kernel<<<(NSRC0 + 255) / 256, 256, 0, stream>>>(user_word, wsort);
    hist_kernel<<<(E0 + 255) / 256, 256, 0, stream>>>(src0, dst0, src1, dst1,
                                                      cnt0, cnt1, degO0, degO1);
    scan_kernel<<<2, 256, 0, stream>>>(cnt0, off0, cur0, cnt1, off1, cur1);
    bucket_kernel<<<(E0 + 255) / 256, 256, 0, stream>>>(src0, dst0, src1, dst1,
                                                        cur0, cur1, esrc0, esrc1);
    embed_kernel<<<NSRC0 / 8, 256, 0, stream>>>(wsort, word_table, degO0, x0);
    agg1_kernel<<<NDST0, 64, 0, stream>>>(off0, esrc0, x0, agg1);
    gemm1_kernel<<<NDST0 / 16, 256, 0, stream>>>(agg1, degO1, W1, b1, h1);
    agg2_kernel<<<NDST1, 64, 0, stream>>>(off1, esrc1, h1, agg2);
    gemm2_kernel<<<(NDST1 + 15) / 16, 256, 0, stream>>>(agg2, W2, b2, labels, (float*)d_out);
}

// Round 6
// 397.505 us; speedup vs baseline: 1.0814x; 1.0814x over previous
//
#include <hip/hip_runtime.h>

#define E0     300000
#define E1     75000
#define NSRC0  50000
#define NDST0  20000
#define NDST1  5000
#define EMB    128
#define HID    256
#define NOUT   16

#define NPB        40     // nodes per embed block (1250 * 40 = 50000 exactly)
#define TILE_SHIFT 12     // 4096-row (2 MB) vocab tiles; 50000 >> 12 -> tiles 0..12

// ---------------- int degree histograms (CSR counts + out-degrees) ----------------
__global__ void hist_kernel(const int* __restrict__ src0, const int* __restrict__ dst0,
                            const int* __restrict__ src1, const int* __restrict__ dst1,
                            int* cnt0, int* cnt1, int* degO0, int* degO1) {
    int i = blockIdx.x * blockDim.x + threadIdx.x;
    if (i < E0) {
        atomicAdd(&cnt0[dst0[i]], 1);
        atomicAdd(&degO0[src0[i]], 1);
    }
    if (i < E1) {
        atomicAdd(&cnt1[dst1[i]], 1);
        atomicAdd(&degO1[src1[i]], 1);
    }
}

// ---------------- exclusive scan (2 blocks: graph0 bins, graph1 bins) ----------------
__device__ void scan_body(const int* __restrict__ cnt, int n,
                          int* __restrict__ off, int* __restrict__ cur) {
    __shared__ int sums[256];
    int t = threadIdx.x;
    int chunk = (n + 255) / 256;
    int lo = t * chunk, hi = min(lo + chunk, n);
    int s = 0;
    for (int i = lo; i < hi; ++i) s += cnt[i];
    sums[t] = s;
    __syncthreads();
    for (int d = 1; d < 256; d <<= 1) {
        int x = (t >= d) ? sums[t - d] : 0;
        __syncthreads();
        sums[t] += x;
        __syncthreads();
    }
    int run = (t == 0) ? 0 : sums[t - 1];
    for (int i = lo; i < hi; ++i) {
        off[i] = run; cur[i] = run;
        run += cnt[i];
    }
    if (t == 255) off[n] = run;
}

__global__ void scan_kernel(const int* cnt0, int* off0, int* cur0,
                            const int* cnt1, int* off1, int* cur1) {
    if (blockIdx.x == 0) scan_body(cnt0, NDST0, off0, cur0);
    else                 scan_body(cnt1, NDST1, off1, cur1);
}

// ---------------- bucket edges by dst (build CSR adjacency) ----------------
__global__ void bucket_kernel(const int* __restrict__ src0, const int* __restrict__ dst0,
                              const int* __restrict__ src1, const int* __restrict__ dst1,
                              int* cur0, int* cur1, int* esrc0, int* esrc1) {
    int i = blockIdx.x * blockDim.x + threadIdx.x;
    if (i < E0) {
        int p = atomicAdd(&cur0[dst0[i]], 1);
        esrc0[p] = src0[i];
    }
    if (i < E1) {
        int p = atomicAdd(&cur1[dst1[i]], 1);
        esrc1[p] = src1[i];
    }
}

// ---------------- fused embedding mean: LDS tile-sort + phase-coherent gather -------
// Grid = 1250 all-resident blocks, 40 nodes/block. Indices counting-sorted by 2MB
// vocab tile in LDS; all blocks start together and sweep tiles in lockstep, so the
// active tile set stays L2-resident per XCD.
__global__ void embed_kernel(const int* __restrict__ user_word,
                             const float* __restrict__ word_table,
                             const int* __restrict__ degO0,
                             float* __restrict__ x0) {
    __shared__ int raw[NPB * 50];
    __shared__ int srt[NPB * 50];
    __shared__ int cnt[NPB * 17];        // stride 17: avoids LDS bank conflicts
    int t = threadIdx.x;
    int base = blockIdx.x * NPB * 50;
    for (int j = t; j < NPB * 50; j += 256)       // coalesced index load
        raw[j] = user_word[base + j];
    for (int j = t; j < NPB * 17; j += 256)
        cnt[j] = 0;
    __syncthreads();
    if (t < NPB) {                                // 1 thread sorts 1 node (in LDS)
        int* c = cnt + t * 17;
        const int* r = raw + t * 50;
        for (int j = 0; j < 50; ++j) c[r[j] >> TILE_SHIFT]++;
        int run = 0;
        for (int b = 0; b < 13; ++b) { int v = c[b]; c[b] = run; run += v; }
        int* o = srt + t * 50;
        for (int j = 0; j < 50; ++j) { int v = r[j]; o[c[v >> TILE_SHIFT]++] = v; }
    }
    __syncthreads();
    int g = t >> 5, l = t & 31;                   // 8 groups of 32 lanes
    const float4* wt = (const float4*)word_table; // row = 32 float4
    for (int n = g; n < NPB; n += 8) {            // 5 nodes per group, in lockstep slots
        const int* id = srt + n * 50;
        float ax = 0.f, ay = 0.f, az = 0.f, aw = 0.f;
        #pragma unroll 2
        for (int j = 0; j < 50; j += 2) {         // 2-edge unroll: 2 loads in flight
            float4 v0 = wt[id[j] * 32 + l];
            float4 v1 = wt[id[j + 1] * 32 + l];
            ax += v0.x + v1.x; ay += v0.y + v1.y;
            az += v0.z + v1.z; aw += v0.w + v1.w;
        }
        int node = blockIdx.x * NPB + n;
        float s = rsqrtf(fmaxf((float)degO0[node], 1.0f)) * 0.02f;  // 1/50 mean
        float4 o4; o4.x = ax * s; o4.y = ay * s; o4.z = az * s; o4.w = aw * s;
        ((float4*)x0)[node * 32 + l] = o4;
    }
}

// ---------------- layer-1 gather-aggregate (float4, 1 wave/dst) ----------------
__global__ void agg1_kernel(const int* __restrict__ off0, const int* __restrict__ esrc0,
                            const float* __restrict__ x0, float* __restrict__ agg1) {
    int d = blockIdx.x;
    int t = threadIdx.x;               // 0..63
    int half = t >> 5, l = t & 31;
    int lo = off0[d], hi = off0[d + 1];
    const float4* x4 = (const float4*)x0;          // row = 32 float4
    float ax = 0.f, ay = 0.f, az = 0.f, aw = 0.f;
    for (int j = lo + half; j < hi; j += 2) {
        float4 v = x4[esrc0[j] * 32 + l];
        ax += v.x; ay += v.y; az += v.z; aw += v.w;
    }
    ax += __shfl_down(ax, 32); ay += __shfl_down(ay, 32);
    az += __shfl_down(az, 32); aw += __shfl_down(aw, 32);
    if (half == 0) {
        float sc = rsqrtf(fmaxf((float)(hi - lo), 1.0f));
        float4 o; o.x = ax * sc; o.y = ay * sc; o.z = az * sc; o.w = aw * sc;
        ((float4*)agg1)[d * 32 + l] = o;
    }
}

// ---------------- GEMM1: h1 = relu(agg1 @ W1 + b1) * rsqrt(deg_out1) ----------------
__global__ void gemm1_kernel(const float* __restrict__ agg1,
                             const int* __restrict__ degO1,
                             const float* __restrict__ W1, const float* __restrict__ b1,
                             float* __restrict__ h1) {
    __shared__ float A[16 * 128];
    __shared__ float s_out[16];
    int row0 = blockIdx.x * 16;
    int t = threadIdx.x;
    if (t < 16)
        s_out[t] = rsqrtf(fmaxf((float)degO1[row0 + t], 1.0f));
    for (int j = t; j < 16 * 128; j += 256)
        A[j] = agg1[row0 * 128 + j];
    __syncthreads();
    float acc[16];
    #pragma unroll
    for (int r = 0; r < 16; ++r) acc[r] = 0.0f;
    for (int k = 0; k < 128; ++k) {
        float w = W1[k * 256 + t];          // coalesced across t
        #pragma unroll
        for (int r = 0; r < 16; ++r)
            acc[r] += A[r * 128 + k] * w;   // LDS broadcast
    }
    float bb = b1[t];
    #pragma unroll
    for (int r = 0; r < 16; ++r)
        h1[(row0 + r) * 256 + t] = fmaxf(acc[r] + bb, 0.0f) * s_out[r];
}

// ---------------- layer-2 gather-aggregate (float4, 1 wave/dst, no reduce) ----------------
__global__ void agg2_kernel(const int* __restrict__ off1, const int* __restrict__ esrc1,
                            const float* __restrict__ h1, float* __restrict__ agg2) {
    int d = blockIdx.x;
    int l = threadIdx.x;               // 0..63
    int lo = off1[d], hi = off1[d + 1];
    const float4* h4 = (const float4*)h1;          // row = 64 float4
    float ax = 0.f, ay = 0.f, az = 0.f, aw = 0.f;
    int j = lo;
    for (; j + 1 < hi; j += 2) {
        float4 v0 = h4[esrc1[j] * 64 + l];
        float4 v1 = h4[esrc1[j + 1] * 64 + l];
        ax += v0.x + v1.x; ay += v0.y + v1.y;
        az += v0.z + v1.z; aw += v0.w + v1.w;
    }
    if (j < hi) {
        float4 v = h4[esrc1[j] * 64 + l];
        ax += v.x; ay += v.y; az += v.z; aw += v.w;
    }
    float sc = rsqrtf(fmaxf((float)(hi - lo), 1.0f));
    float4 o; o.x = ax * sc; o.y = ay * sc; o.z = az * sc; o.w = aw * sc;
    ((float4*)agg2)[d * 64 + l] = o;
}

// ---------------- GEMM2: out = relu(agg2 @ W2 + b2)  (+ labels passthrough) ----------------
__global__ void gemm2_kernel(const float* __restrict__ agg2,
                             const float* __restrict__ W2, const float* __restrict__ b2,
                             const int* __restrict__ labels,
                             float* __restrict__ out) {
    __shared__ float A[16 * 257];       // +1 pad: kills 16-way bank conflict
    __shared__ float Wl[256 * 16];
    int row0 = blockIdx.x * 16;
    int t = threadIdx.x;
    for (int j = t; j < 256 * 16; j += 256) Wl[j] = W2[j];
    for (int j = t; j < 16 * 256; j += 256) {
        int r = j >> 8, k = j & 255;
        int row = row0 + r;
        A[r * 257 + k] = (row < NDST1) ? agg2[row * 256 + k] : 0.0f;
    }
    __syncthreads();
    int r = t >> 4, c = t & 15;
    float acc = 0.0f;
    for (int k = 0; k < 256; ++k)
        acc += A[r * 257 + k] * Wl[k * 16 + c];
    int row = row0 + r;
    if (row < NDST1)
        out[row * NOUT + c] = fmaxf(acc + b2[c], 0.0f);
    if (t < 16 && row0 + t < NDST1)
        out[NDST1 * NOUT + row0 + t] = (float)labels[row0 + t];
}

extern "C" void kernel_launch(void* const* d_in, const int* in_sizes, int n_in,
                              void* d_out, int out_size, void* d_ws, size_t ws_size,
                              hipStream_t stream) {
    const int*   user_word  = (const int*)d_in[0];
    const int*   labels     = (const int*)d_in[1];
    const int*   src0       = (const int*)d_in[2];
    const int*   dst0       = (const int*)d_in[3];
    const int*   src1       = (const int*)d_in[4];
    const int*   dst1       = (const int*)d_in[5];
    const float* word_table = (const float*)d_in[6];
    const float* W1         = (const float*)d_in[7];
    const float* b1         = (const float*)d_in[8];
    const float* W2         = (const float*)d_in[9];
    const float* b2         = (const float*)d_in[10];

    int* iws = (int*)d_ws;
    int* cnt0  = iws;            // 20000  ┐
    int* cnt1  = iws + 20000;    //  5000  │ zeroed (95000 ints)
    int* degO0 = iws + 25000;    // 50000  │
    int* degO1 = iws + 75000;    // 20000  ┘
    int* off0  = iws + 95000;    // 20001
    int* off1  = iws + 115001;   //  5001
    int* cur0  = iws + 120002;   // 20000
    int* cur1  = iws + 140002;   //  5000
    int* esrc0 = iws + 145002;   // 300000
    int* esrc1 = iws + 445002;   // 75000   (end 520002; pad to 520004 for 16B align)
    float* x0   = (float*)(iws + 520004); // 6400000 (50000*128)
    float* agg1 = x0 + 6400000;           // 2560000 (20000*128)
    float* h1   = x0;                     // alias: x0 dead after agg1_kernel
    float* agg2 = agg1 + 2560000;         // 1280000 (5000*256)

    hipMemsetAsync(iws, 0, 95000 * sizeof(int), stream);

    hist_kernel<<<(E0 + 255) / 256, 256, 0, stream>>>(src0, dst0, src1, dst1,
                                                      cnt0, cnt1, degO0, degO1);
    scan_kernel<<<2, 256, 0, stream>>>(cnt0, off0, cur0, cnt1, off1, cur1);
    bucket_kernel<<<(E0 + 255) / 256, 256, 0, stream>>>(src0, dst0, src1, dst1,
                                                        cur0, cur1, esrc0, esrc1);
    embed_kernel<<<NSRC0 / NPB, 256, 0, stream>>>(user_word, word_table, degO0, x0);
    agg1_kernel<<<NDST0, 64, 0, stream>>>(off0, esrc0, x0, agg1);
    gemm1_kernel<<<NDST0 / 16, 256, 0, stream>>>(agg1, degO1, W1, b1, h1);
    agg2_kernel<<<NDST1, 64, 0, stream>>>(off1, esrc1, h1, agg2);
    gemm2_kernel<<<(NDST1 + 15) / 16, 256, 0, stream>>>(agg2, W2, b2, labels, (float*)d_out);
}

// Round 7
// 338.692 us; speedup vs baseline: 1.2692x; 1.1736x over previous
//
#include <hip/hip_runtime.h>

#define E0     300000
#define E1     75000
#define NSRC0  50000
#define NDST0  20000
#define NDST1  5000
#define EMB    128
#define HID    256
#define NOUT   16

#define NPB        40     // nodes per embed block (1250 * 40 = 50000 exactly)
#define TILE_SHIFT 12     // 4096-row vocab tiles (2MB f32 / 1MB bf16); tiles 0..12

// ---- bf16 helpers (RNE pack, cheap unpack) ----
__device__ __forceinline__ unsigned short f2bf(float f) {
    unsigned u = __float_as_uint(f);
    return (unsigned short)((u + 0x7FFFu + ((u >> 16) & 1u)) >> 16);
}
__device__ __forceinline__ float bflo(unsigned u) { return __uint_as_float(u << 16); }
__device__ __forceinline__ float bfhi(unsigned u) { return __uint_as_float(u & 0xFFFF0000u); }
__device__ __forceinline__ unsigned pack2(float a, float b) {
    return (unsigned)f2bf(a) | ((unsigned)f2bf(b) << 16);
}

// ---------------- f32 -> bf16 table conversion (8 floats/thread) ----------------
__global__ void tconv_kernel(const float* __restrict__ wt, unsigned short* __restrict__ wtb) {
    int i = blockIdx.x * blockDim.x + threadIdx.x;   // 800000 threads
    const float4* in = (const float4*)wt;
    float4 v0 = in[i * 2], v1 = in[i * 2 + 1];
    uint4 o;
    o.x = pack2(v0.x, v0.y); o.y = pack2(v0.z, v0.w);
    o.z = pack2(v1.x, v1.y); o.w = pack2(v1.z, v1.w);
    ((uint4*)wtb)[i] = o;
}

// ---------------- int degree histograms (CSR counts + out-degrees) ----------------
__global__ void hist_kernel(const int* __restrict__ src0, const int* __restrict__ dst0,
                            const int* __restrict__ src1, const int* __restrict__ dst1,
                            int* cnt0, int* cnt1, int* degO0, int* degO1) {
    int i = blockIdx.x * blockDim.x + threadIdx.x;
    if (i < E0) {
        atomicAdd(&cnt0[dst0[i]], 1);
        atomicAdd(&degO0[src0[i]], 1);
    }
    if (i < E1) {
        atomicAdd(&cnt1[dst1[i]], 1);
        atomicAdd(&degO1[src1[i]], 1);
    }
}

// ---------------- exclusive scan (2 blocks: graph0 bins, graph1 bins) ----------------
__device__ void scan_body(const int* __restrict__ cnt, int n,
                          int* __restrict__ off, int* __restrict__ cur) {
    __shared__ int sums[256];
    int t = threadIdx.x;
    int chunk = (n + 255) / 256;
    int lo = t * chunk, hi = min(lo + chunk, n);
    int s = 0;
    for (int i = lo; i < hi; ++i) s += cnt[i];
    sums[t] = s;
    __syncthreads();
    for (int d = 1; d < 256; d <<= 1) {
        int x = (t >= d) ? sums[t - d] : 0;
        __syncthreads();
        sums[t] += x;
        __syncthreads();
    }
    int run = (t == 0) ? 0 : sums[t - 1];
    for (int i = lo; i < hi; ++i) {
        off[i] = run; cur[i] = run;
        run += cnt[i];
    }
    if (t == 255) off[n] = run;
}

__global__ void scan_kernel(const int* cnt0, int* off0, int* cur0,
                            const int* cnt1, int* off1, int* cur1) {
    if (blockIdx.x == 0) scan_body(cnt0, NDST0, off0, cur0);
    else                 scan_body(cnt1, NDST1, off1, cur1);
}

// ---------------- bucket edges by dst (build CSR adjacency) ----------------
__global__ void bucket_kernel(const int* __restrict__ src0, const int* __restrict__ dst0,
                              const int* __restrict__ src1, const int* __restrict__ dst1,
                              int* cur0, int* cur1, int* esrc0, int* esrc1) {
    int i = blockIdx.x * blockDim.x + threadIdx.x;
    if (i < E0) {
        int p = atomicAdd(&cur0[dst0[i]], 1);
        esrc0[p] = src0[i];
    }
    if (i < E1) {
        int p = atomicAdd(&cur1[dst1[i]], 1);
        esrc1[p] = src1[i];
    }
}

// ---------------- fused embedding mean: LDS tile-sort + bf16 gather -------
// 1250 all-resident blocks, 40 nodes/block, 8 groups of 32 lanes.
// bf16 row = 256B = 32 lanes x uint2 (4 bf16/lane).
__global__ void embed_kernel(const int* __restrict__ user_word,
                             const unsigned short* __restrict__ wtb,
                             const int* __restrict__ degO0,
                             unsigned short* __restrict__ x0b) {
    __shared__ int raw[NPB * 50];
    __shared__ int srt[NPB * 50];
    __shared__ int cnt[NPB * 17];        // stride 17: avoids LDS bank conflicts
    int t = threadIdx.x;
    int base = blockIdx.x * NPB * 50;
    for (int j = t; j < NPB * 50; j += 256)       // coalesced index load
        raw[j] = user_word[base + j];
    for (int j = t; j < NPB * 17; j += 256)
        cnt[j] = 0;
    __syncthreads();
    if (t < NPB) {                                // 1 thread sorts 1 node (in LDS)
        int* c = cnt + t * 17;
        const int* r = raw + t * 50;
        for (int j = 0; j < 50; ++j) c[r[j] >> TILE_SHIFT]++;
        int run = 0;
        for (int b = 0; b < 13; ++b) { int v = c[b]; c[b] = run; run += v; }
        int* o = srt + t * 50;
        for (int j = 0; j < 50; ++j) { int v = r[j]; o[c[v >> TILE_SHIFT]++] = v; }
    }
    __syncthreads();
    int g = t >> 5, l = t & 31;                   // 8 groups of 32 lanes
    const uint2* wt2 = (const uint2*)wtb;         // row = 32 uint2
    for (int n = g; n < NPB; n += 8) {            // 5 nodes per group
        const int* id = srt + n * 50;
        float a0 = 0.f, a1 = 0.f, a2 = 0.f, a3 = 0.f;
        #pragma unroll 2
        for (int j = 0; j < 50; j += 2) {         // 2 loads in flight
            uint2 v0 = wt2[id[j] * 32 + l];
            uint2 v1 = wt2[id[j + 1] * 32 + l];
            a0 += bflo(v0.x) + bflo(v1.x); a1 += bfhi(v0.x) + bfhi(v1.x);
            a2 += bflo(v0.y) + bflo(v1.y); a3 += bfhi(v0.y) + bfhi(v1.y);
        }
        int node = blockIdx.x * NPB + n;
        float s = rsqrtf(fmaxf((float)degO0[node], 1.0f)) * 0.02f;  // 1/50 mean
        uint2 o2; o2.x = pack2(a0 * s, a1 * s); o2.y = pack2(a2 * s, a3 * s);
        ((uint2*)x0b)[node * 32 + l] = o2;
    }
}

// ---------------- layer-1 gather-aggregate (bf16 in, f32 out, 1 wave/dst) ----------
__global__ void agg1_kernel(const int* __restrict__ off0, const int* __restrict__ esrc0,
                            const unsigned short* __restrict__ x0b,
                            float* __restrict__ agg1) {
    int d = blockIdx.x;
    int t = threadIdx.x;               // 0..63
    int half = t >> 5, l = t & 31;
    int lo = off0[d], hi = off0[d + 1];
    const uint2* x2 = (const uint2*)x0b;           // row = 32 uint2
    float a0 = 0.f, a1 = 0.f, a2 = 0.f, a3 = 0.f;
    for (int j = lo + half; j < hi; j += 2) {
        uint2 v = x2[esrc0[j] * 32 + l];
        a0 += bflo(v.x); a1 += bfhi(v.x); a2 += bflo(v.y); a3 += bfhi(v.y);
    }
    a0 += __shfl_down(a0, 32); a1 += __shfl_down(a1, 32);
    a2 += __shfl_down(a2, 32); a3 += __shfl_down(a3, 32);
    if (half == 0) {
        float sc = rsqrtf(fmaxf((float)(hi - lo), 1.0f));
        float4 o; o.x = a0 * sc; o.y = a1 * sc; o.z = a2 * sc; o.w = a3 * sc;
        ((float4*)agg1)[d * 32 + l] = o;
    }
}

// ---------------- GEMM1: h1 = relu(agg1 @ W1 + b1) * rsqrt(deg_out1), bf16 out ------
__global__ void gemm1_kernel(const float* __restrict__ agg1,
                             const int* __restrict__ degO1,
                             const float* __restrict__ W1, const float* __restrict__ b1,
                             unsigned short* __restrict__ h1b) {
    __shared__ float A[16 * 128];
    __shared__ float s_out[16];
    int row0 = blockIdx.x * 16;
    int t = threadIdx.x;
    if (t < 16)
        s_out[t] = rsqrtf(fmaxf((float)degO1[row0 + t], 1.0f));
    for (int j = t; j < 16 * 128; j += 256)
        A[j] = agg1[row0 * 128 + j];
    __syncthreads();
    float acc[16];
    #pragma unroll
    for (int r = 0; r < 16; ++r) acc[r] = 0.0f;
    for (int k = 0; k < 128; ++k) {
        float w = W1[k * 256 + t];          // coalesced across t
        #pragma unroll
        for (int r = 0; r < 16; ++r)
            acc[r] += A[r * 128 + k] * w;   // LDS broadcast
    }
    float bb = b1[t];
    #pragma unroll
    for (int r = 0; r < 16; ++r)
        h1b[(row0 + r) * 256 + t] = f2bf(fmaxf(acc[r] + bb, 0.0f) * s_out[r]);
}

// ---------------- layer-2 gather-aggregate (bf16 in, f32 out, 1 wave/dst) -----------
// bf16 row = 512B = 64 lanes x uint2.
__global__ void agg2_kernel(const int* __restrict__ off1, const int* __restrict__ esrc1,
                            const unsigned short* __restrict__ h1b,
                            float* __restrict__ agg2) {
    int d = blockIdx.x;
    int l = threadIdx.x;               // 0..63
    int lo = off1[d], hi = off1[d + 1];
    const uint2* h2 = (const uint2*)h1b;           // row = 64 uint2
    float a0 = 0.f, a1 = 0.f, a2 = 0.f, a3 = 0.f;
    int j = lo;
    for (; j + 1 < hi; j += 2) {
        uint2 v0 = h2[esrc1[j] * 64 + l];
        uint2 v1 = h2[esrc1[j + 1] * 64 + l];
        a0 += bflo(v0.x) + bflo(v1.x); a1 += bfhi(v0.x) + bfhi(v1.x);
        a2 += bflo(v0.y) + bflo(v1.y); a3 += bfhi(v0.y) + bfhi(v1.y);
    }
    if (j < hi) {
        uint2 v = h2[esrc1[j] * 64 + l];
        a0 += bflo(v.x); a1 += bfhi(v.x); a2 += bflo(v.y); a3 += bfhi(v.y);
    }
    float sc = rsqrtf(fmaxf((float)(hi - lo), 1.0f));
    float4 o; o.x = a0 * sc; o.y = a1 * sc; o.z = a2 * sc; o.w = a3 * sc;
    ((float4*)agg2)[d * 64 + l] = o;
}

// ---------------- GEMM2: out = relu(agg2 @ W2 + b2)  (+ labels passthrough) ----------
__global__ void gemm2_kernel(const float* __restrict__ agg2,
                             const float* __restrict__ W2, const float* __restrict__ b2,
                             const int* __restrict__ labels,
                             float* __restrict__ out) {
    __shared__ float A[16 * 257];       // +1 pad: kills 16-way bank conflict
    __shared__ float Wl[256 * 16];
    int row0 = blockIdx.x * 16;
    int t = threadIdx.x;
    for (int j = t; j < 256 * 16; j += 256) Wl[j] = W2[j];
    for (int j = t; j < 16 * 256; j += 256) {
        int r = j >> 8, k = j & 255;
        int row = row0 + r;
        A[r * 257 + k] = (row < NDST1) ? agg2[row * 256 + k] : 0.0f;
    }
    __syncthreads();
    int r = t >> 4, c = t & 15;
    float acc = 0.0f;
    for (int k = 0; k < 256; ++k)
        acc += A[r * 257 + k] * Wl[k * 16 + c];
    int row = row0 + r;
    if (row < NDST1)
        out[row * NOUT + c] = fmaxf(acc + b2[c], 0.0f);
    if (t < 16 && row0 + t < NDST1)
        out[NDST1 * NOUT + row0 + t] = (float)labels[row0 + t];
}

extern "C" void kernel_launch(void* const* d_in, const int* in_sizes, int n_in,
                              void* d_out, int out_size, void* d_ws, size_t ws_size,
                              hipStream_t stream) {
    const int*   user_word  = (const int*)d_in[0];
    const int*   labels     = (const int*)d_in[1];
    const int*   src0       = (const int*)d_in[2];
    const int*   dst0       = (const int*)d_in[3];
    const int*   src1       = (const int*)d_in[4];
    const int*   dst1       = (const int*)d_in[5];
    const float* word_table = (const float*)d_in[6];
    const float* W1         = (const float*)d_in[7];
    const float* b1         = (const float*)d_in[8];
    const float* W2         = (const float*)d_in[9];
    const float* b2         = (const float*)d_in[10];

    int* iws = (int*)d_ws;
    int* cnt0  = iws;            // 20000  ┐
    int* cnt1  = iws + 20000;    //  5000  │ zeroed (95000 ints)
    int* degO0 = iws + 25000;    // 50000  │
    int* degO1 = iws + 75000;    // 20000  ┘
    int* off0  = iws + 95000;    // 20001
    int* off1  = iws + 115001;   //  5001
    int* cur0  = iws + 120002;   // 20000
    int* cur1  = iws + 140002;   //  5000
    int* esrc0 = iws + 145002;   // 300000
    int* esrc1 = iws + 445002;   // 75000   (end 520002; pad to 520004)
    unsigned short* wtb  = (unsigned short*)(iws + 520004);   // 6.4M bf16 = 3.2M ints
    unsigned short* x0b  = (unsigned short*)(iws + 3720004);  // 6.4M bf16 = 3.2M ints
    float*          agg1 = (float*)(iws + 6920004);           // 2.56M f32
    unsigned short* h1b  = (unsigned short*)(iws + 9480004);  // 5.12M bf16 = 2.56M ints
    float*          agg2 = (float*)(iws + 12040004);          // 1.28M f32 (end 13320004 ≈ 53.3 MB)

    hipMemsetAsync(iws, 0, 95000 * sizeof(int), stream);

    tconv_kernel<<<(NSRC0 * EMB / 8 + 255) / 256, 256, 0, stream>>>(word_table, wtb);
    hist_kernel<<<(E0 + 255) / 256, 256, 0, stream>>>(src0, dst0, src1, dst1,
                                                      cnt0, cnt1, degO0, degO1);
    scan_kernel<<<2, 256, 0, stream>>>(cnt0, off0, cur0, cnt1, off1, cur1);
    bucket_kernel<<<(E0 + 255) / 256, 256, 0, stream>>>(src0, dst0, src1, dst1,
                                                        cur0, cur1, esrc0, esrc1);
    embed_kernel<<<NSRC0 / NPB, 256, 0, stream>>>(user_word, wtb, degO0, x0b);
    agg1_kernel<<<NDST0, 64, 0, stream>>>(off0, esrc0, x0b, agg1);
    gemm1_kernel<<<NDST0 / 16, 256, 0, stream>>>(agg1, degO1, W1, b1, h1b);
    agg2_kernel<<<NDST1, 64, 0, stream>>>(off1, esrc1, h1b, agg2);
    gemm2_kernel<<<(NDST1 + 15) / 16, 256, 0, stream>>>(agg2, W2, b2, labels, (float*)d_out);
}